// Round 13
// baseline (147.065 us; speedup 1.0000x reference)
//
#include <hip/hip_runtime.h>

// ---------------------------------------------------------------------------
// RelativeAttention: out = softmax(QK^T*scale + relbias + mask) V, + proj
// B=4 H=8 N=2048 C=512 hd=64.  bf16 MFMA pipeline, f32 accum.
// R13: R12 (32x32 MFMA + in-register P via permlane32_swap, no Ps LDS) with
//      the P rounding path fixed: explicit round-to-nearest f32->bf16 pack
//      (cvt_pk's rounding mode was the suspected 7.3e-3 bias) AND l summed
//      from the ROUNDED P values so any residual rounding bias cancels in
//      O = sum(P V)/l. Layout identical to R12.
// ---------------------------------------------------------------------------

typedef __attribute__((ext_vector_type(8))) short short8;    // 8 bf16
typedef __attribute__((ext_vector_type(4))) float f32x4;     // 16x16 C/D
typedef __attribute__((ext_vector_type(16))) float f32x16;   // 32x32 C/D

#define SEQ   2048
#define NHEAD 8
#define NBATCH 4
#define HD    64
#define CDIM  512
#define L2E   1.44269504f
#define SC    0.18033688f   // 0.125 * log2(e)

__device__ __forceinline__ unsigned short f32_to_bf16_rn(float f) {
  unsigned u = __builtin_bit_cast(unsigned, f);
  u += 0x7FFFu + ((u >> 16) & 1u);
  return (unsigned short)(u >> 16);
}
__device__ __forceinline__ float bf16_to_f32(unsigned short h) {
  unsigned u = ((unsigned)h) << 16;
  return __builtin_bit_cast(float, u);
}
__device__ __forceinline__ f32x16 zero16() {
  f32x16 z;
#pragma unroll
  for (int i = 0; i < 16; ++i) z[i] = 0.f;
  return z;
}

// -------------------------------- f32 -> bf16 convert (vectorized) ----------
__global__ __launch_bounds__(256) void cvt_f32_bf16(const float* __restrict__ in,
                                                    ushort* __restrict__ out, int n4) {
  int i = blockIdx.x * 256 + threadIdx.x;
  const int stride = gridDim.x * 256;
  for (; i < n4; i += stride) {
    float4 v = reinterpret_cast<const float4*>(in)[i];
    ushort4 o;
    o.x = f32_to_bf16_rn(v.x);
    o.y = f32_to_bf16_rn(v.y);
    o.z = f32_to_bf16_rn(v.z);
    o.w = f32_to_bf16_rn(v.w);
    reinterpret_cast<ushort4*>(out)[i] = o;
  }
}

// -------------------------------- NT GEMM: C = A(MxK) * B(NxK)^T ------------
template <int MODE>
__global__ __launch_bounds__(256) void gemm_nt(
    const ushort* __restrict__ A, const ushort* __restrict__ Bm,
    ushort* __restrict__ qo, ushort* __restrict__ ko, ushort* __restrict__ vto,
    const float* __restrict__ bias, float* __restrict__ outf) {
  const int K = 512;
  __shared__ ushort As[128 * 40];
  __shared__ ushort Bs[128 * 40];

  const int t = threadIdx.x;
  const int bn = blockIdx.x, bm = blockIdx.y;
  const int lane = t & 63, w = t >> 6;
  const int wm = w >> 1, wn = w & 1;
  const int lr = lane & 15, lq = lane >> 4;
  const int m0 = bm * 128, n0 = bn * 128;

  f32x4 acc[4][4];
#pragma unroll
  for (int i = 0; i < 4; ++i)
#pragma unroll
    for (int j = 0; j < 4; ++j) acc[i][j] = (f32x4){0.f, 0.f, 0.f, 0.f};

  for (int kt = 0; kt < K; kt += 32) {
#pragma unroll
    for (int p = 0; p < 2; ++p) {
      const int flat = p * 256 + t;
      const int row = flat >> 2, seg = flat & 3;
      *(uint4*)&As[row * 40 + seg * 8] =
          *(const uint4*)(A + (size_t)(m0 + row) * K + kt + seg * 8);
      *(uint4*)&Bs[row * 40 + seg * 8] =
          *(const uint4*)(Bm + (size_t)(n0 + row) * K + kt + seg * 8);
    }
    __syncthreads();

    short8 af[4], bf[4];
#pragma unroll
    for (int i = 0; i < 4; ++i) {
      af[i] = *(const short8*)&As[(wm * 64 + i * 16 + lr) * 40 + lq * 8];
      bf[i] = *(const short8*)&Bs[(wn * 64 + i * 16 + lr) * 40 + lq * 8];
    }
#pragma unroll
    for (int i = 0; i < 4; ++i)
#pragma unroll
      for (int j = 0; j < 4; ++j)
        acc[i][j] = __builtin_amdgcn_mfma_f32_16x16x32_bf16(af[i], bf[j], acc[i][j], 0, 0, 0);
    __syncthreads();
  }

  if constexpr (MODE == 0) {
#pragma unroll
    for (int i = 0; i < 4; ++i) {
      const int mbase = m0 + wm * 64 + i * 16 + lq * 4;  // + r
      const int bb = mbase >> 11;
      const int s0 = mbase & 2047;
#pragma unroll
      for (int j = 0; j < 4; ++j) {
        const int nb = n0 + wn * 64 + j * 16;
        const int tt = nb >> 9;
        const int hh = (nb >> 6) & 7;
        const int d0 = nb & 63;
        const int bh = bb * NHEAD + hh;
        if (tt == 2) {
          ushort4 pk;
          pk.x = f32_to_bf16_rn(acc[i][j][0]);
          pk.y = f32_to_bf16_rn(acc[i][j][1]);
          pk.z = f32_to_bf16_rn(acc[i][j][2]);
          pk.w = f32_to_bf16_rn(acc[i][j][3]);
          *(ushort4*)(vto + ((size_t)bh * HD + d0 + lr) * SEQ + s0) = pk;
        } else {
          ushort* dst = (tt == 0) ? qo : ko;
#pragma unroll
          for (int r = 0; r < 4; ++r)
            dst[((size_t)bh * SEQ + s0 + r) * HD + d0 + lr] = f32_to_bf16_rn(acc[i][j][r]);
        }
      }
    }
  } else {
#pragma unroll
    for (int i = 0; i < 4; ++i) {
#pragma unroll
      for (int j = 0; j < 4; ++j) {
        const int n = n0 + wn * 64 + j * 16 + lr;
        const float bv = bias[n];
#pragma unroll
        for (int r = 0; r < 4; ++r) {
          const int m = m0 + wm * 64 + i * 16 + lq * 4 + r;
          outf[(size_t)m * 512 + n] = acc[i][j][r] + bv;
        }
      }
    }
  }
}

// -------------------------------- fused flash attention ---------------------
// Grid 512 (XCD-swizzled). 256 threads = 4 waves; wave w owns q-rows
// w*32..w*32+31; lane's q = qbase + (lane&31), hi = lane>>5 picks kv halves.
// kv tiles of 64 (two 32-kv subtiles u), K/V double-buffered in LDS, one
// barrier per tile. QK: S = mfma_32x32x16(K, Q); P kept IN-REGISTER via
// explicit-RN pack + permlane32_swap; PV: O = mfma_32x32x16(P, V). No Ps LDS.
__global__ __launch_bounds__(256) void attn_fused(
    const ushort* __restrict__ Q, const ushort* __restrict__ Kt,
    const ushort* __restrict__ VT, const float* __restrict__ mask,
    const float* __restrict__ Btab, ushort* __restrict__ Out) {
  __shared__ ushort Ks[2][64 * 72];    // 18432 B
  __shared__ ushort Vs[2][64 * 72];    // 18432 B  -> total 36864 B

  const int flat = blockIdx.x;         // 512 blocks
  const int xcd = flat & 7;
  const int rr = flat >> 3;            // 0..63
  const int h = rr & 7;
  const int slot = rr >> 3;            // 0..7
  const int g = slot * 8 + xcd;        // 0..63  (b,qt) group
  const int qt = g & 15, b = g >> 4;

  const int bh = b * NHEAD + h;
  const ushort* qh = Q + (size_t)bh * SEQ * HD;
  const ushort* kh = Kt + (size_t)bh * SEQ * HD;
  const ushort* vh = VT + (size_t)bh * HD * SEQ;
  const float* mb = mask + (size_t)b * SEQ * SEQ;
  const float* bt = Btab + h * (2 * SEQ - 1);

  const int t = threadIdx.x;
  const int lane = t & 63, w = t >> 6;       // 4 waves
  const int la = lane & 31, hi = lane >> 5;
  const int qb0 = qt * 128;
  const int qbase = qb0 + w * 32;            // wave's 32 q-rows
  const int q = qbase + la;                  // this lane's q-row

  // Q fragments: B-operand of mfma(K,Q): col=la=q, k=16c+8hi+j
  short8 qf0, qf1, qf2, qf3;
  {
    const ushort* qp = qh + (size_t)q * HD + hi * 8;
    qf0 = *(const short8*)(qp);
    qf1 = *(const short8*)(qp + 16);
    qf2 = *(const short8*)(qp + 32);
    qf3 = *(const short8*)(qp + 48);
  }

  // mask/bias vector bases (lane's q-row); element kv = kv0+32u+8s+4hi+r
  const float* mv = mb + (size_t)q * SEQ + 4 * hi;        // + kv0+32u+8s
  const float* bv = bt + q + 2044 - 4 * hi;               // - kv0-32u-8s, [3-r]

  float lacc0 = 0.f, lacc1 = 0.f;
  f32x16 of0 = zero16(), of1 = zero16();     // O cols d=la (v=0) / d=32+la

  const int srow = t >> 3;           // staging row 0..31 (+32 second half)
  const int sseg = t & 7;            // staging 16B segment

  const ushort* kp = kh + (size_t)srow * HD + sseg * 8;   // + kv*HD (+32*HD)
  const ushort* vp = vh + (size_t)srow * SEQ + sseg * 8;  // + kv (+32*SEQ)

  // prologue: tile0 -> regs -> buf0; then tile1 -> regs
  uint4 kr0 = *(const uint4*)(kp);
  uint4 kr1 = *(const uint4*)(kp + 32 * HD);
  uint4 vr0 = *(const uint4*)(vp);
  uint4 vr1 = *(const uint4*)(vp + 32 * SEQ);
  *(uint4*)&Ks[0][srow * 72 + sseg * 8] = kr0;
  *(uint4*)&Ks[0][(32 + srow) * 72 + sseg * 8] = kr1;
  *(uint4*)&Vs[0][srow * 72 + sseg * 8] = vr0;
  *(uint4*)&Vs[0][(32 + srow) * 72 + sseg * 8] = vr1;
  kr0 = *(const uint4*)(kp + 64 * HD);
  kr1 = *(const uint4*)(kp + 96 * HD);
  vr0 = *(const uint4*)(vp + 64);
  vr1 = *(const uint4*)(vp + 64 + 32 * SEQ);

  // tile-0 u=0 mask/bias prefetch (LOAD-ONLY)
  float4 mn0[4], bn0[4];
#pragma unroll
  for (int s = 0; s < 4; ++s) {
    mn0[s] = *(const float4*)(mv + s * 8);
    bn0[s] = *(const float4*)(bv - s * 8);
  }

  for (int it = 0; it < 32; ++it) {
    const int kv0 = it * 64;
    const int cur = it & 1, nxt = cur ^ 1;

    __syncthreads();

    // write tile it+1 (in regs) into buf[nxt]
    *(uint4*)&Ks[nxt][srow * 72 + sseg * 8] = kr0;
    *(uint4*)&Ks[nxt][(32 + srow) * 72 + sseg * 8] = kr1;
    *(uint4*)&Vs[nxt][srow * 72 + sseg * 8] = vr0;
    *(uint4*)&Vs[nxt][(32 + srow) * 72 + sseg * 8] = vr1;

    // u=1 mask/bias for THIS tile (LOAD-ONLY; wait sinks to SM u1)
    float4 mn1[4], bn1[4];
#pragma unroll
    for (int s = 0; s < 4; ++s) {
      mn1[s] = *(const float4*)(mv + kv0 + 32 + s * 8);
      bn1[s] = *(const float4*)(bv - kv0 - 32 - s * 8);
    }

    // issue tile it+2 staging loads (clamped)
    const int lkv = (it + 2 < 32) ? (it + 2) * 64 : 0;
    kr0 = *(const uint4*)(kp + (size_t)lkv * HD);
    kr1 = *(const uint4*)(kp + (size_t)(lkv + 32) * HD);
    vr0 = *(const uint4*)(vp + lkv);
    vr1 = *(const uint4*)(vp + lkv + 32 * SEQ);

    // ---- QK u=0: S[kv][q] ----
    f32x16 sf0 = zero16();
#pragma unroll
    for (int c = 0; c < 4; ++c) {
      const short8 kf = *(const short8*)&Ks[cur][(la)*72 + c * 16 + hi * 8];
      sf0 = (c == 0)
        ? __builtin_amdgcn_mfma_f32_32x32x16_bf16(kf, qf0, sf0, 0, 0, 0)
        : (c == 1)
        ? __builtin_amdgcn_mfma_f32_32x32x16_bf16(kf, qf1, sf0, 0, 0, 0)
        : (c == 2)
        ? __builtin_amdgcn_mfma_f32_32x32x16_bf16(kf, qf2, sf0, 0, 0, 0)
        : __builtin_amdgcn_mfma_f32_32x32x16_bf16(kf, qf3, sf0, 0, 0, 0);
    }

    // ---- softmax u=0 + RN pack (kv(reg) = 8*(reg>>2) + (reg&3) + 4*hi) ----
    unsigned pk0, pk1, pk2, pk3, pk4, pk5, pk6, pk7;
#pragma unroll
    for (int s = 0; s < 4; ++s) {
      unsigned bb_[4];
#pragma unroll
      for (int r = 0; r < 4; ++r) {
        const float mbv = (&mn0[s].x)[r] + (&bn0[s].x)[3 - r];
        const float p = __builtin_amdgcn_exp2f(fmaf(sf0[4 * s + r], SC, mbv * L2E));
        const unsigned short pb = f32_to_bf16_rn(p);
        lacc0 += bf16_to_f32(pb);     // l from ROUNDED P: bias cancels in O
        bb_[r] = pb;
      }
      const unsigned d0 = bb_[0] | (bb_[1] << 16);
      const unsigned d1 = bb_[2] | (bb_[3] << 16);
      if (s == 0) { pk0 = d0; pk1 = d1; }
      else if (s == 1) { pk2 = d0; pk3 = d1; }
      else if (s == 2) { pk4 = d0; pk5 = d1; }
      else { pk6 = d0; pk7 = d1; }
    }
    // permlane swaps: pa0 <- blocks(s=0,1) = kv 0..15, pa1 <- (s=2,3) = 16..31
    asm("v_permlane32_swap_b32 %0, %1" : "+v"(pk0), "+v"(pk2));
    asm("v_permlane32_swap_b32 %0, %1" : "+v"(pk1), "+v"(pk3));
    asm("v_permlane32_swap_b32 %0, %1" : "+v"(pk4), "+v"(pk6));
    asm("v_permlane32_swap_b32 %0, %1" : "+v"(pk5), "+v"(pk7));
    union { uint4 u; short8 s8; } pa0, pa1;
    pa0.u.x = pk0; pa0.u.y = pk1; pa0.u.z = pk2; pa0.u.w = pk3;
    pa1.u.x = pk4; pa1.u.y = pk5; pa1.u.z = pk6; pa1.u.w = pk7;

    // u=0 mask/bias prefetch for NEXT tile (LOAD-ONLY), clamped
    const int mkv = (it + 1 < 32) ? (it + 1) * 64 : 0;
#pragma unroll
    for (int s = 0; s < 4; ++s) {
      mn0[s] = *(const float4*)(mv + mkv + s * 8);
      bn0[s] = *(const float4*)(bv - mkv - s * 8);
    }

    // ---- QK u=1 ----
    f32x16 sf1 = zero16();
#pragma unroll
    for (int c = 0; c < 4; ++c) {
      const short8 kf = *(const short8*)&Ks[cur][(32 + la) * 72 + c * 16 + hi * 8];
      sf1 = (c == 0)
        ? __builtin_amdgcn_mfma_f32_32x32x16_bf16(kf, qf0, sf1, 0, 0, 0)
        : (c == 1)
        ? __builtin_amdgcn_mfma_f32_32x32x16_bf16(kf, qf1, sf1, 0, 0, 0)
        : (c == 2)
        ? __builtin_amdgcn_mfma_f32_32x32x16_bf16(kf, qf2, sf1, 0, 0, 0)
        : __builtin_amdgcn_mfma_f32_32x32x16_bf16(kf, qf3, sf1, 0, 0, 0);
    }

    // ---- softmax u=1 + RN pack ----
    unsigned qk0, qk1, qk2, qk3, qk4, qk5, qk6, qk7;
#pragma unroll
    for (int s = 0; s < 4; ++s) {
      unsigned bb_[4];
#pragma unroll
      for (int r = 0; r < 4; ++r) {
        const float mbv = (&mn1[s].x)[r] + (&bn1[s].x)[3 - r];
        const float p = __builtin_amdgcn_exp2f(fmaf(sf1[4 * s + r], SC, mbv * L2E));
        const unsigned short pb = f32_to_bf16_rn(p);
        lacc1 += bf16_to_f32(pb);
        bb_[r] = pb;
      }
      const unsigned d0 = bb_[0] | (bb_[1] << 16);
      const unsigned d1 = bb_[2] | (bb_[3] << 16);
      if (s == 0) { qk0 = d0; qk1 = d1; }
      else if (s == 1) { qk2 = d0; qk3 = d1; }
      else if (s == 2) { qk4 = d0; qk5 = d1; }
      else { qk6 = d0; qk7 = d1; }
    }
    asm("v_permlane32_swap_b32 %0, %1" : "+v"(qk0), "+v"(qk2));
    asm("v_permlane32_swap_b32 %0, %1" : "+v"(qk1), "+v"(qk3));
    asm("v_permlane32_swap_b32 %0, %1" : "+v"(qk4), "+v"(qk6));
    asm("v_permlane32_swap_b32 %0, %1" : "+v"(qk5), "+v"(qk7));
    union { uint4 u; short8 s8; } pa2, pa3;
    pa2.u.x = qk0; pa2.u.y = qk1; pa2.u.z = qk2; pa2.u.w = qk3;
    pa3.u.x = qk4; pa3.u.y = qk5; pa3.u.z = qk6; pa3.u.w = qk7;

    // ---- PV: O += P V  (A=P[q][kv], B=V[kv][d]; 4 k-steps x 2 d-tiles) ----
#pragma unroll
    for (int tt = 0; tt < 4; ++tt) {
      const short8 pf = (tt == 0) ? pa0.s8 : (tt == 1) ? pa1.s8
                       : (tt == 2) ? pa2.s8 : pa3.s8;
      const short8 vf0 = *(const short8*)&Vs[cur][(la)*72 + tt * 16 + hi * 8];
      const short8 vf1 = *(const short8*)&Vs[cur][(32 + la) * 72 + tt * 16 + hi * 8];
      of0 = __builtin_amdgcn_mfma_f32_32x32x16_bf16(pf, vf0, of0, 0, 0, 0);
      of1 = __builtin_amdgcn_mfma_f32_32x32x16_bf16(pf, vf1, of1, 0, 0, 0);
    }
  }

  // l total: lanes la and la+32 hold the two kv-halves of q=qbase+la
  float lt = lacc0 + lacc1;
  lt += __shfl_xor(lt, 32);

  // write: of row (reg) -> q_local = (reg&3)+8*(reg>>2)+4*hi; col d = 32v+la
  ushort* ob = Out + ((size_t)(b * SEQ + qbase)) * CDIM + h * HD + la;
#pragma unroll
  for (int reg = 0; reg < 16; ++reg) {
    const int ql = ((reg & 3) + 8 * (reg >> 2)) + 4 * hi;
    const float inv = 1.0f / __shfl(lt, ql);
    ushort* op = ob + (size_t)ql * CDIM;
    op[0] = f32_to_bf16_rn(of0[reg] * inv);
    op[32] = f32_to_bf16_rn(of1[reg] * inv);
  }
}

// ---------------------------------------------------------------------------
extern "C" void kernel_launch(void* const* d_in, const int* in_sizes, int n_in,
                              void* d_out, int out_size, void* d_ws, size_t ws_size,
                              hipStream_t stream) {
  const float* x     = (const float*)d_in[0];
  const float* mask  = (const float*)d_in[1];
  const float* Wqkv  = (const float*)d_in[2];
  const float* Btab  = (const float*)d_in[3];
  const float* Wproj = (const float*)d_in[4];
  const float* bproj = (const float*)d_in[5];
  float* out = (float*)d_out;

  char* ws = (char*)d_ws;
  const size_t SZ_X   = (size_t)NBATCH * SEQ * CDIM;
  const size_t SZ_QKV = (size_t)3 * CDIM * CDIM;
  const size_t SZ_PRJ = (size_t)CDIM * CDIM;
  const size_t SZ_HD  = (size_t)NBATCH * NHEAD * SEQ * HD;

  ushort* xb    = (ushort*)ws; ws += SZ_X * 2;
  ushort* wqkvb = (ushort*)ws; ws += SZ_QKV * 2;
  ushort* wprjb = (ushort*)ws; ws += SZ_PRJ * 2;
  ushort* qb    = (ushort*)ws; ws += SZ_HD * 2;
  ushort* kb    = (ushort*)ws; ws += SZ_HD * 2;
  ushort* vtb   = (ushort*)ws; ws += SZ_HD * 2;
  ushort* aob   = (ushort*)ws; ws += SZ_X * 2;

  {
    int n4 = (int)(SZ_X / 4);
    int g = (n4 + 255) / 256; if (g > 4096) g = 4096;
    cvt_f32_bf16<<<g, 256, 0, stream>>>(x, xb, n4);
  }
  {
    int n4 = (int)(SZ_QKV / 4);
    cvt_f32_bf16<<<(n4 + 255) / 256, 256, 0, stream>>>(Wqkv, wqkvb, n4);
  }
  {
    int n4 = (int)(SZ_PRJ / 4);
    cvt_f32_bf16<<<(n4 + 255) / 256, 256, 0, stream>>>(Wproj, wprjb, n4);
  }

  // QKV: M=8192, N=1536, K=512
  gemm_nt<0><<<dim3(12, 64), 256, 0, stream>>>(xb, wqkvb, qb, kb, vtb, nullptr, nullptr);

  // fused attention (1D swizzled grid, 256-thread blocks, 128 q-rows each)
  attn_fused<<<dim3(512), 256, 0, stream>>>(qb, kb, vtb, mask, Btab, aob);

  // proj: M=8192, N=512, K=512, +bias, f32 out
  gemm_nt<1><<<dim3(4, 64), 256, 0, stream>>>(aob, wprjb, nullptr, nullptr, nullptr, bproj, out);
}